// Round 8
// baseline (56.916 us; speedup 1.0000x reference)
//
#include <hip/hip_runtime.h>
#include <math.h>

// Problem constants
#define NCH   128      // DIM
#define HH    128
#define WW    128
#define NB    8        // batch
#define NBH   4        // batches per grid-half
#define KS    7
#define MSIZE (128*7*128)        // [u][b][c]

typedef float f32x4 __attribute__((ext_vector_type(4)));

// Separable DFT intermediates: M[u,b,c] = sum_a K[a,b,c] * exp(-2pi i * u*(a-3)/128)
__device__ float g_MAr[MSIZE];
__device__ float g_MAi[MSIZE];
__device__ float g_MBr[MSIZE];
__device__ float g_MBi[MSIZE];

// Kernel 1: build M arrays (A gets 0.9*tanh(A*decay) applied first).
__global__ void kern_factor(const float* __restrict__ A, const float* __restrict__ B) {
    int idx = blockIdx.x * blockDim.x + threadIdx.x;
    if (idx >= MSIZE) return;
    int c  = idx & 127;
    int ub = idx >> 7;
    int b  = ub % 7;
    int u  = ub / 7;

    const float W0 = -6.283185307179586f / 128.0f;
    float mar = 0.f, mai = 0.f, mbr = 0.f, mbi = 0.f;
    float db = (float)(b - 3);
#pragma unroll
    for (int a = 0; a < 7; ++a) {
        float da   = (float)(a - 3);
        float dist = sqrtf(da * da + db * db);
        float dec  = expf(-0.1f * dist);          // exp(-0.3*dist/center), center=3
        float ka   = 0.9f * tanhf(A[c * 49 + a * 7 + b] * dec);
        float kb   = B[c * 49 + a * 7 + b];
        float th   = W0 * (float)(u * (a - 3));
        float s, cc;
        sincosf(th, &s, &cc);                     // exp(i*th) = cc + i*s
        mar = fmaf(ka, cc, mar);
        mai = fmaf(ka, s,  mai);
        mbr = fmaf(kb, cc, mbr);
        mbi = fmaf(kb, s,  mbi);
    }
    g_MAr[idx] = mar;
    g_MAi[idx] = mai;
    g_MBr[idx] = mbr;
    g_MBi[idx] = mbi;
}

// Kernel 2 (fused): finish DFT -> C in registers, apply to 4 batches per block.
// Grid = 4096 (2 rounds/CU). Stream phase: issue ALL 8 global_load_dwordx4,
// then ONE asm with all 8 results as "+v" operands -> all 8 must be
// simultaneously live => all 8 loads in flight before the first consume.
__global__ void kern_main(const float* __restrict__ x, float* __restrict__ out) {
    __shared__ float s_cs[128];
    __shared__ float s_sn[128];
    int t = threadIdx.x;
    if (t < 128) {
        float th = (6.283185307179586f / 128.0f) * (float)t;
        float s, c;
        sincosf(th, &s, &c);
        s_cs[t] = c;
        s_sn[t] = s;
    }
    __syncthreads();

    int bid  = blockIdx.x;             // 0..4095
    int half = bid >> 11;              // 0 or 1
    int uv   = bid & 2047;             // 0..2047
    int u    = uv >> 4;                // 0..127
    int v    = ((uv & 15) << 3) + (t >> 5);   // 0..127
    int c0   = (t & 31) << 2;          // 0,4,...,124

    float Afr[4] = {0, 0, 0, 0}, Afi[4] = {0, 0, 0, 0};
    float Bfr[4] = {0, 0, 0, 0}, Bfi[4] = {0, 0, 0, 0};

#pragma unroll
    for (int b = 0; b < 7; ++b) {
        int p = (v * (b - 3)) & 127;           // mod 128
        float wr = s_cs[p];
        float wi = -s_sn[p];                   // exp(-2pi i p/128)
        int mbase = (u * 7 + b) * 128 + c0;
        f32x4 mar = *(const f32x4*)(g_MAr + mbase);
        f32x4 mai = *(const f32x4*)(g_MAi + mbase);
        f32x4 mbr = *(const f32x4*)(g_MBr + mbase);
        f32x4 mbi = *(const f32x4*)(g_MBi + mbase);
#pragma unroll
        for (int j = 0; j < 4; ++j) {
            Afr[j] = fmaf(mar[j], wr, fmaf(-mai[j], wi, Afr[j]));
            Afi[j] = fmaf(mar[j], wi, fmaf( mai[j], wr, Afi[j]));
            Bfr[j] = fmaf(mbr[j], wr, fmaf(-mbi[j], wi, Bfr[j]));
            Bfi[j] = fmaf(mbr[j], wi, fmaf( mbi[j], wr, Bfi[j]));
        }
    }

    // S = (1+A)(1+A^2)(1+A^4)(1+A^8); C = S*Bf
    f32x4 cr, ci;
#pragma unroll
    for (int j = 0; j < 4; ++j) {
        float ar = Afr[j], ai = Afi[j];
        float a2r = ar * ar - ai * ai,     a2i = 2.f * ar * ai;
        float a4r = a2r * a2r - a2i * a2i, a4i = 2.f * a2r * a2i;
        float a8r = a4r * a4r - a4i * a4i, a8i = 2.f * a4r * a4i;
        float s1r = 1.f + ar,  s1i = ai;
        float s2r = 1.f + a2r, s2i = a2i;
        float pr  = s1r * s2r - s1i * s2i;
        float pi  = s1r * s2i + s1i * s2r;
        float s3r = 1.f + a4r, s3i = a4i;
        float qr  = pr * s3r - pi * s3i;
        float qi  = pr * s3i + pi * s3r;
        float s4r = 1.f + a8r, s4i = a8i;
        float Sr  = qr * s4r - qi * s4i;
        float Si  = qr * s4i + qi * s4r;
        cr[j] = Sr * Bfr[j] - Si * Bfi[j];
        ci[j] = Sr * Bfi[j] + Si * Bfr[j];
    }

    // Stream 4 batches: all 8 loads in flight, single materialization fence,
    // then compute + NT-store.
    const size_t BS = (size_t)HH * WW * 2 * NCH;      // batch stride in floats
    size_t base = ((size_t)u * WW + v) * (2 * NCH) + c0 + (size_t)(half * NBH) * BS;

    f32x4 xr0 = *(const f32x4*)(x + base + 0 * BS);
    f32x4 xi0 = *(const f32x4*)(x + base + 0 * BS + NCH);
    f32x4 xr1 = *(const f32x4*)(x + base + 1 * BS);
    f32x4 xi1 = *(const f32x4*)(x + base + 1 * BS + NCH);
    f32x4 xr2 = *(const f32x4*)(x + base + 2 * BS);
    f32x4 xi2 = *(const f32x4*)(x + base + 2 * BS + NCH);
    f32x4 xr3 = *(const f32x4*)(x + base + 3 * BS);
    f32x4 xi3 = *(const f32x4*)(x + base + 3 * BS + NCH);
    asm volatile("" : "+v"(xr0), "+v"(xi0), "+v"(xr1), "+v"(xi1),
                      "+v"(xr2), "+v"(xi2), "+v"(xr3), "+v"(xi3));

    f32x4 xr[NBH] = {xr0, xr1, xr2, xr3};
    f32x4 xi[NBH] = {xi0, xi1, xi2, xi3};
#pragma unroll
    for (int bt = 0; bt < NBH; ++bt) {
        f32x4 orr, oii;
#pragma unroll
        for (int j = 0; j < 4; ++j) {
            orr[j] = cr[j] * xr[bt][j] - ci[j] * xi[bt][j];
            oii[j] = cr[j] * xi[bt][j] + ci[j] * xr[bt][j];
        }
        __builtin_nontemporal_store(orr, (f32x4*)(out + base + (size_t)bt * BS));
        __builtin_nontemporal_store(oii, (f32x4*)(out + base + (size_t)bt * BS + NCH));
    }
}

extern "C" void kernel_launch(void* const* d_in, const int* in_sizes, int n_in,
                              void* d_out, int out_size, void* d_ws, size_t ws_size,
                              hipStream_t stream) {
    const float* x = (const float*)d_in[0];   // (8,128,128,256) f32
    const float* A = (const float*)d_in[1];   // (128,7,7) f32
    const float* B = (const float*)d_in[2];   // (128,7,7) f32
    float* out = (float*)d_out;

    kern_factor<<<(MSIZE + 255) / 256, 256, 0, stream>>>(A, B);
    kern_main<<<4096, 256, 0, stream>>>(x, out);
}

// Round 9
// 54.616 us; speedup vs baseline: 1.0421x; 1.0421x over previous
//
#include <hip/hip_runtime.h>
#include <math.h>
#include <stdint.h>

// Problem constants
#define NCH   128      // DIM
#define HH    128
#define WW    128
#define NB    8        // batch
#define NBH   4        // batches per grid-half
#define KS    7
#define MSIZE (128*7*128)        // [u][b][c]

typedef float f32x4 __attribute__((ext_vector_type(4)));

// Explicit async global load: compiler does not auto-wait on these.
#define GLOAD(dst, addr) \
    asm volatile("global_load_dwordx4 %0, %1, off" : "=v"(dst) : "v"(addr))

// Separable DFT intermediates: M[u,b,c] = sum_a K[a,b,c] * exp(-2pi i * u*(a-3)/128)
__device__ float g_MAr[MSIZE];
__device__ float g_MAi[MSIZE];
__device__ float g_MBr[MSIZE];
__device__ float g_MBi[MSIZE];

// Kernel 1: build M arrays (A gets 0.9*tanh(A*decay) applied first).
__global__ void kern_factor(const float* __restrict__ A, const float* __restrict__ B) {
    int idx = blockIdx.x * blockDim.x + threadIdx.x;
    if (idx >= MSIZE) return;
    int c  = idx & 127;
    int ub = idx >> 7;
    int b  = ub % 7;
    int u  = ub / 7;

    const float W0 = -6.283185307179586f / 128.0f;
    float mar = 0.f, mai = 0.f, mbr = 0.f, mbi = 0.f;
    float db = (float)(b - 3);
#pragma unroll
    for (int a = 0; a < 7; ++a) {
        float da   = (float)(a - 3);
        float dist = sqrtf(da * da + db * db);
        float dec  = expf(-0.1f * dist);          // exp(-0.3*dist/center), center=3
        float ka   = 0.9f * tanhf(A[c * 49 + a * 7 + b] * dec);
        float kb   = B[c * 49 + a * 7 + b];
        float th   = W0 * (float)(u * (a - 3));
        float s, cc;
        sincosf(th, &s, &cc);                     // exp(i*th) = cc + i*s
        mar = fmaf(ka, cc, mar);
        mai = fmaf(ka, s,  mai);
        mbr = fmaf(kb, cc, mbr);
        mbi = fmaf(kb, s,  mbi);
    }
    g_MAr[idx] = mar;
    g_MAi[idx] = mai;
    g_MBr[idx] = mbr;
    g_MBi[idx] = mbi;
}

// Kernel 2 (fused): finish DFT -> C in registers, apply to 4 batches per block.
// Stream phase: 8 inline-asm global_load_dwordx4 issued back-to-back (true
// 8-deep MLP), one s_waitcnt vmcnt(0) + sched_barrier(0), then compute+NT-store.
__global__ void kern_main(const float* __restrict__ x, float* __restrict__ out) {
    __shared__ float s_cs[128];
    __shared__ float s_sn[128];
    int t = threadIdx.x;
    if (t < 128) {
        float th = (6.283185307179586f / 128.0f) * (float)t;
        float s, c;
        sincosf(th, &s, &c);
        s_cs[t] = c;
        s_sn[t] = s;
    }
    __syncthreads();

    int bid  = blockIdx.x;             // 0..4095
    int half = bid >> 11;              // 0 or 1
    int uv   = bid & 2047;             // 0..2047
    int u    = uv >> 4;                // 0..127
    int v    = ((uv & 15) << 3) + (t >> 5);   // 0..127
    int c0   = (t & 31) << 2;          // 0,4,...,124

    float Afr[4] = {0, 0, 0, 0}, Afi[4] = {0, 0, 0, 0};
    float Bfr[4] = {0, 0, 0, 0}, Bfi[4] = {0, 0, 0, 0};

#pragma unroll
    for (int b = 0; b < 7; ++b) {
        int p = (v * (b - 3)) & 127;           // mod 128
        float wr = s_cs[p];
        float wi = -s_sn[p];                   // exp(-2pi i p/128)
        int mbase = (u * 7 + b) * 128 + c0;
        f32x4 mar = *(const f32x4*)(g_MAr + mbase);
        f32x4 mai = *(const f32x4*)(g_MAi + mbase);
        f32x4 mbr = *(const f32x4*)(g_MBr + mbase);
        f32x4 mbi = *(const f32x4*)(g_MBi + mbase);
#pragma unroll
        for (int j = 0; j < 4; ++j) {
            Afr[j] = fmaf(mar[j], wr, fmaf(-mai[j], wi, Afr[j]));
            Afi[j] = fmaf(mar[j], wi, fmaf( mai[j], wr, Afi[j]));
            Bfr[j] = fmaf(mbr[j], wr, fmaf(-mbi[j], wi, Bfr[j]));
            Bfi[j] = fmaf(mbr[j], wi, fmaf( mbi[j], wr, Bfi[j]));
        }
    }

    // S = (1+A)(1+A^2)(1+A^4)(1+A^8); C = S*Bf
    f32x4 cr, ci;
#pragma unroll
    for (int j = 0; j < 4; ++j) {
        float ar = Afr[j], ai = Afi[j];
        float a2r = ar * ar - ai * ai,     a2i = 2.f * ar * ai;
        float a4r = a2r * a2r - a2i * a2i, a4i = 2.f * a2r * a2i;
        float a8r = a4r * a4r - a4i * a4i, a8i = 2.f * a4r * a4i;
        float s1r = 1.f + ar,  s1i = ai;
        float s2r = 1.f + a2r, s2i = a2i;
        float pr  = s1r * s2r - s1i * s2i;
        float pi  = s1r * s2i + s1i * s2r;
        float s3r = 1.f + a4r, s3i = a4i;
        float qr  = pr * s3r - pi * s3i;
        float qi  = pr * s3i + pi * s3r;
        float s4r = 1.f + a8r, s4i = a8i;
        float Sr  = qr * s4r - qi * s4i;
        float Si  = qr * s4i + qi * s4r;
        cr[j] = Sr * Bfr[j] - Si * Bfi[j];
        ci[j] = Sr * Bfi[j] + Si * Bfr[j];
    }

    // Stream 4 batches with forced 8-deep MLP.
    const size_t BS = (size_t)HH * WW * 2 * NCH;      // batch stride in floats
    size_t base = ((size_t)u * WW + v) * (2 * NCH) + c0 + (size_t)(half * NBH) * BS;

    uint64_t a0 = (uint64_t)(x + base + 0 * BS);
    uint64_t b0 = (uint64_t)(x + base + 0 * BS + NCH);
    uint64_t a1 = (uint64_t)(x + base + 1 * BS);
    uint64_t b1 = (uint64_t)(x + base + 1 * BS + NCH);
    uint64_t a2 = (uint64_t)(x + base + 2 * BS);
    uint64_t b2 = (uint64_t)(x + base + 2 * BS + NCH);
    uint64_t a3 = (uint64_t)(x + base + 3 * BS);
    uint64_t b3 = (uint64_t)(x + base + 3 * BS + NCH);

    f32x4 xr0, xi0, xr1, xi1, xr2, xi2, xr3, xi3;
    GLOAD(xr0, a0);  GLOAD(xi0, b0);
    GLOAD(xr1, a1);  GLOAD(xi1, b1);
    GLOAD(xr2, a2);  GLOAD(xi2, b2);
    GLOAD(xr3, a3);  GLOAD(xi3, b3);
    asm volatile("s_waitcnt vmcnt(0)" ::: "memory");
    __builtin_amdgcn_sched_barrier(0);     // nothing crosses the wait (rule #18)

    f32x4 xr[NBH] = {xr0, xr1, xr2, xr3};
    f32x4 xi[NBH] = {xi0, xi1, xi2, xi3};
#pragma unroll
    for (int bt = 0; bt < NBH; ++bt) {
        f32x4 orr, oii;
#pragma unroll
        for (int j = 0; j < 4; ++j) {
            orr[j] = cr[j] * xr[bt][j] - ci[j] * xi[bt][j];
            oii[j] = cr[j] * xi[bt][j] + ci[j] * xr[bt][j];
        }
        __builtin_nontemporal_store(orr, (f32x4*)(out + base + (size_t)bt * BS));
        __builtin_nontemporal_store(oii, (f32x4*)(out + base + (size_t)bt * BS + NCH));
    }
}

extern "C" void kernel_launch(void* const* d_in, const int* in_sizes, int n_in,
                              void* d_out, int out_size, void* d_ws, size_t ws_size,
                              hipStream_t stream) {
    const float* x = (const float*)d_in[0];   // (8,128,128,256) f32
    const float* A = (const float*)d_in[1];   // (128,7,7) f32
    const float* B = (const float*)d_in[2];   // (128,7,7) f32
    float* out = (float*)d_out;

    kern_factor<<<(MSIZE + 255) / 256, 256, 0, stream>>>(A, B);
    kern_main<<<4096, 256, 0, stream>>>(x, out);
}